// Round 1
// baseline (3653.118 us; speedup 1.0000x reference)
//
#include <hip/hip_runtime.h>
#include <hip/hip_bf16.h>
#include <cstdint>
#include <cstddef>

// Problem constants
#define KBLK 6
#define SL 257
#define BA 64
#define DM 1024
#define NHEAD 16
#define DRED 256
#define HDM 16
#define MR (SL * BA)     // 16448 real rows
#define MP 16512         // 129 * 128 padded rows
#define LNEPS 1e-5f

typedef __hip_bfloat16 bf16;
typedef __attribute__((ext_vector_type(8))) short short8;
typedef __attribute__((ext_vector_type(4))) short short4_t;
typedef __attribute__((ext_vector_type(4))) float f32x4;

// ---------------- async global -> LDS (16B per lane) ----------------
__device__ __forceinline__ void gld_lds16(const void* g, void* l) {
  __builtin_amdgcn_global_load_lds(
      (const __attribute__((address_space(1))) unsigned int*)g,
      (__attribute__((address_space(3))) unsigned int*)l, 16, 0, 0);
}

// ---------------- weight casts ----------------
__global__ __launch_bounds__(256) void cast_bf16_kernel(const float* __restrict__ src,
                                                        bf16* __restrict__ dst, int n) {
  int i = blockIdx.x * 256 + threadIdx.x;
  int stride = gridDim.x * 256;
  for (; i < n; i += stride) dst[i] = __float2bfloat16(src[i]);
}

__global__ __launch_bounds__(256) void cast_projT_kernel(const float* __restrict__ proj,
                                                         bf16* __restrict__ dst) {
  // proj: (DM, 768) -> dst: (768, DM)
  int i = blockIdx.x * 256 + threadIdx.x;
  if (i < 768 * DM) {
    int n = i >> 10, k = i & (DM - 1);
    dst[i] = __float2bfloat16(proj[k * 768 + n]);
  }
}

// ---------------- LayerNorm (+gate) ----------------
// MODE 0: x = hook; LN(x) -> hout
// MODE 1: x = wm*hook + (1-wm)*x; LN(x) -> hout
// MODE 2: LN(x) -> hout
// MODE 3: LN(x) -> hout at transposed row (b*SL+s)  [ln_post]
template <int MODE>
__global__ __launch_bounds__(256) void ln_kernel(
    const float* __restrict__ hook, const float* __restrict__ alpha, int kidx,
    float* __restrict__ x, bf16* __restrict__ hout,
    const float* __restrict__ w, const float* __restrict__ bb) {
  const int row = blockIdx.x;
  const int tid = threadIdx.x;
  const size_t base = (size_t)row * DM + tid * 4;
  float4 v;
  if (MODE == 0) {
    v = *(const float4*)(hook + base);
    *(float4*)(x + base) = v;
  } else if (MODE == 1) {
    const float wm = 1.f / (1.f + __expf(-alpha[kidx] * 10.f));
    const float om = 1.f - wm;
    float4 hv = *(const float4*)(hook + base);
    float4 xv = *(const float4*)(x + base);
    v.x = wm * hv.x + om * xv.x;
    v.y = wm * hv.y + om * xv.y;
    v.z = wm * hv.z + om * xv.z;
    v.w = wm * hv.w + om * xv.w;
    *(float4*)(x + base) = v;
  } else {
    v = *(const float4*)(x + base);
  }
  float s1 = v.x + v.y + v.z + v.w;
  float s2 = v.x * v.x + v.y * v.y + v.z * v.z + v.w * v.w;
#pragma unroll
  for (int o = 32; o >= 1; o >>= 1) {
    s1 += __shfl_down(s1, o);
    s2 += __shfl_down(s2, o);
  }
  __shared__ float red[8];
  if ((tid & 63) == 0) {
    red[tid >> 6] = s1;
    red[4 + (tid >> 6)] = s2;
  }
  __syncthreads();
  s1 = red[0] + red[1] + red[2] + red[3];
  s2 = red[4] + red[5] + red[6] + red[7];
  const float mu = s1 * (1.f / DM);
  const float rs = rsqrtf(s2 * (1.f / DM) - mu * mu + LNEPS);
  size_t orow = row;
  if (MODE == 3) {
    int s = row >> 6, b2 = row & 63;
    orow = (size_t)b2 * SL + s;
  }
  const int c = tid * 4;
  float vals[4] = {v.x, v.y, v.z, v.w};
  short4_t pk;
#pragma unroll
  for (int j = 0; j < 4; ++j) {
    float hv = (vals[j] - mu) * rs * w[c + j] + bb[c + j];
    bf16 t = __float2bfloat16(hv);
    pk[j] = *reinterpret_cast<short*>(&t);
  }
  *(short4_t*)((char*)hout + (orow * DM + c) * 2) = pk;
}

// ---------------- attention (per-head, two-pass softmax, fp32 VALU) ----------------
__device__ __forceinline__ float dot16(const float* __restrict__ q, const float* kr) {
  float4 k0 = *(const float4*)(kr);
  float4 k1 = *(const float4*)(kr + 4);
  float4 k2 = *(const float4*)(kr + 8);
  float4 k3 = *(const float4*)(kr + 12);
  float s = q[0] * k0.x;
  s = fmaf(q[1], k0.y, s); s = fmaf(q[2], k0.z, s); s = fmaf(q[3], k0.w, s);
  s = fmaf(q[4], k1.x, s); s = fmaf(q[5], k1.y, s); s = fmaf(q[6], k1.z, s); s = fmaf(q[7], k1.w, s);
  s = fmaf(q[8], k2.x, s); s = fmaf(q[9], k2.y, s); s = fmaf(q[10], k2.z, s); s = fmaf(q[11], k2.w, s);
  s = fmaf(q[12], k3.x, s); s = fmaf(q[13], k3.y, s); s = fmaf(q[14], k3.z, s); s = fmaf(q[15], k3.w, s);
  return s;
}

__global__ __launch_bounds__(256) void attn_kernel(const float* __restrict__ qkv,
                                                   bf16* __restrict__ obuf) {
  __shared__ float kl[SL][HDM];
  __shared__ float vl[SL][HDM];
  const int bh = blockIdx.x;
  const int b = bh >> 4, h = bh & 15;
  const int tid = threadIdx.x;
  for (int idx = tid; idx < SL * HDM; idx += 256) {
    int s = idx >> 4, d = idx & 15;
    const float* row = qkv + (size_t)(s * BA + b) * 768;
    kl[s][d] = row[DRED + h * HDM + d];
    vl[s][d] = row[2 * DRED + h * HDM + d];
  }
  __syncthreads();
  for (int t = tid; t < SL; t += 256) {
    const float* qrow = qkv + (size_t)(t * BA + b) * 768 + h * HDM;
    float q[16];
    {
      float4 q0 = *(const float4*)(qrow);
      float4 q1 = *(const float4*)(qrow + 4);
      float4 q2 = *(const float4*)(qrow + 8);
      float4 q3 = *(const float4*)(qrow + 12);
      q[0] = q0.x * 0.25f; q[1] = q0.y * 0.25f; q[2] = q0.z * 0.25f; q[3] = q0.w * 0.25f;
      q[4] = q1.x * 0.25f; q[5] = q1.y * 0.25f; q[6] = q1.z * 0.25f; q[7] = q1.w * 0.25f;
      q[8] = q2.x * 0.25f; q[9] = q2.y * 0.25f; q[10] = q2.z * 0.25f; q[11] = q2.w * 0.25f;
      q[12] = q3.x * 0.25f; q[13] = q3.y * 0.25f; q[14] = q3.z * 0.25f; q[15] = q3.w * 0.25f;
    }
    float mx = -3.4e38f;
#pragma unroll 4
    for (int s = 0; s < SL; ++s) mx = fmaxf(mx, dot16(q, &kl[s][0]));
    float l = 0.f;
    float o[16];
#pragma unroll
    for (int d = 0; d < 16; ++d) o[d] = 0.f;
#pragma unroll 2
    for (int s = 0; s < SL; ++s) {
      float sc = dot16(q, &kl[s][0]);
      float p = __expf(sc - mx);
      l += p;
      float4 v0 = *(const float4*)&vl[s][0];
      float4 v1 = *(const float4*)&vl[s][4];
      float4 v2 = *(const float4*)&vl[s][8];
      float4 v3 = *(const float4*)&vl[s][12];
      o[0] = fmaf(p, v0.x, o[0]); o[1] = fmaf(p, v0.y, o[1]); o[2] = fmaf(p, v0.z, o[2]); o[3] = fmaf(p, v0.w, o[3]);
      o[4] = fmaf(p, v1.x, o[4]); o[5] = fmaf(p, v1.y, o[5]); o[6] = fmaf(p, v1.z, o[6]); o[7] = fmaf(p, v1.w, o[7]);
      o[8] = fmaf(p, v2.x, o[8]); o[9] = fmaf(p, v2.y, o[9]); o[10] = fmaf(p, v2.z, o[10]); o[11] = fmaf(p, v2.w, o[11]);
      o[12] = fmaf(p, v3.x, o[12]); o[13] = fmaf(p, v3.y, o[13]); o[14] = fmaf(p, v3.z, o[14]); o[15] = fmaf(p, v3.w, o[15]);
    }
    float inv = 1.f / l;
    bf16* orow = obuf + (size_t)(t * BA + b) * DRED + h * HDM;
    short8 p0, p1;
#pragma unroll
    for (int d = 0; d < 8; ++d) {
      bf16 t0 = __float2bfloat16(o[d] * inv);
      bf16 t1 = __float2bfloat16(o[d + 8] * inv);
      p0[d] = *reinterpret_cast<short*>(&t0);
      p1[d] = *reinterpret_cast<short*>(&t1);
    }
    *(short8*)(orow) = p0;
    *(short8*)(orow + 8) = p1;
  }
}

// ---------------- GEMM: C(M,N) = A(M,K) * Bw(N,K)^T + bias ----------------
// EPI 0: write fp32 C (+bias)
// EPI 1: C(fp32) += acc + bias   (residual accumulate)
// EPI 2: write bf16 quickgelu(acc+bias)
// EPI 3: write bf16 (acc+bias)
template <int EPI>
__global__ __launch_bounds__(256) void gemm_kernel(
    const bf16* __restrict__ A, int lda,
    const bf16* __restrict__ Bw, int ldb,
    const float* __restrict__ bias,
    void* __restrict__ C, int ldc,
    int Kdim, int Mreal) {
  __shared__ char lds[2 * 32768];  // [buf][A 16KB | B 16KB], BK=64
  const int tid = threadIdx.x;
  const int wave = tid >> 6, lane = tid & 63;
  const int lrow = lane & 15, lk = lane >> 4;
  const int wr = wave >> 1, wc = wave & 1;
  const int m0 = blockIdx.x * 128;
  const int n0 = blockIdx.y * 128;

  f32x4 acc[4][4];
  const f32x4 zero = {0.f, 0.f, 0.f, 0.f};
#pragma unroll
  for (int i = 0; i < 4; ++i)
#pragma unroll
    for (int j = 0; j < 4; ++j) acc[i][j] = zero;

  const int nk = Kdim >> 6;

  auto stage = [&](int buf, int kt) {
    const int k0 = kt << 6;
#pragma unroll
    for (int j = 0; j < 4; ++j) {
      int c = wave * 256 + j * 64 + lane;
      int row = c >> 3, segp = c & 7;
      int seg = segp ^ (row & 7);
      const bf16* ga = A + (size_t)(m0 + row) * lda + k0 + seg * 8;
      gld_lds16(ga, &lds[buf * 32768 + (wave * 256 + j * 64) * 16]);
      const bf16* gb = Bw + (size_t)(n0 + row) * ldb + k0 + seg * 8;
      gld_lds16(gb, &lds[buf * 32768 + 16384 + (wave * 256 + j * 64) * 16]);
    }
  };

  stage(0, 0);
  __syncthreads();
  int cur = 0;
  for (int kt = 0; kt < nk; ++kt) {
    if (kt + 1 < nk) stage(cur ^ 1, kt + 1);
    const char* aL = &lds[cur * 32768];
    const char* bL = aL + 16384;
#pragma unroll
    for (int kh = 0; kh < 2; ++kh) {
      short8 af[4], bfr[4];
#pragma unroll
      for (int i = 0; i < 4; ++i) {
        int r = wr * 64 + i * 16 + lrow;
        int seg = kh * 4 + lk;
        af[i] = *(const short8*)(aL + r * 128 + ((seg ^ (r & 7)) << 4));
      }
#pragma unroll
      for (int j = 0; j < 4; ++j) {
        int r = wc * 64 + j * 16 + lrow;
        int seg = kh * 4 + lk;
        bfr[j] = *(const short8*)(bL + r * 128 + ((seg ^ (r & 7)) << 4));
      }
#pragma unroll
      for (int i = 0; i < 4; ++i)
#pragma unroll
        for (int j = 0; j < 4; ++j)
          acc[i][j] = __builtin_amdgcn_mfma_f32_16x16x32_bf16(af[i], bfr[j], acc[i][j], 0, 0, 0);
    }
    __syncthreads();
    cur ^= 1;
  }

#pragma unroll
  for (int i = 0; i < 4; ++i) {
#pragma unroll
    for (int j = 0; j < 4; ++j) {
      int col = n0 + wc * 64 + j * 16 + lrow;
      float bv = bias ? bias[col] : 0.f;
#pragma unroll
      for (int r = 0; r < 4; ++r) {
        int row = m0 + wr * 64 + i * 16 + lk * 4 + r;
        if (row < Mreal) {
          float v = acc[i][j][r] + bv;
          size_t off = (size_t)row * ldc + col;
          if (EPI == 0) {
            ((float*)C)[off] = v;
          } else if (EPI == 1) {
            float* p = (float*)C + off;
            *p += v;
          } else if (EPI == 2) {
            float g = v / (1.f + __expf(-1.702f * v));
            ((bf16*)C)[off] = __float2bfloat16(g);
          } else {
            ((bf16*)C)[off] = __float2bfloat16(v);
          }
        }
      }
    }
  }
}

// ---------------- driver ----------------
extern "C" void kernel_launch(void* const* d_in, const int* in_sizes, int n_in,
                              void* d_out, int out_size, void* d_ws, size_t ws_size,
                              hipStream_t stream) {
  const float* hook = (const float*)d_in[0];
  const float* alpha = (const float*)d_in[1];
  const float* ipw = (const float*)d_in[2];
  const float* ipb = (const float*)d_in[3];
  const float* opw = (const float*)d_in[4];
  const float* opb = (const float*)d_in[5];
  const float* l1w = (const float*)d_in[6];
  const float* l1b = (const float*)d_in[7];
  const float* l2w = (const float*)d_in[8];
  const float* l2b = (const float*)d_in[9];
  const float* fcw = (const float*)d_in[10];
  const float* fcb = (const float*)d_in[11];
  const float* cpw = (const float*)d_in[12];
  const float* cpb = (const float*)d_in[13];
  const float* lpw = (const float*)d_in[14];
  const float* lpb = (const float*)d_in[15];
  const float* proj = (const float*)d_in[16];

  char* ws = (char*)d_ws;
  size_t off = 0;
  float* x = (float*)(ws + off); off += (size_t)MP * DM * 4;
  bf16* hbuf = (bf16*)(ws + off); off += (size_t)MP * DM * 2;
  float* qkv = (float*)(ws + off);
  bf16* mbuf = (bf16*)qkv;  // reuse qkv region for MLP intermediate (bf16)
  off += (size_t)MP * 768 * 4;
  bf16* obuf = (bf16*)(ws + off); off += (size_t)MP * DRED * 2;
  bf16* wq = (bf16*)(ws + off); off += (size_t)KBLK * 768 * DM * 2;
  bf16* wo = (bf16*)(ws + off); off += (size_t)KBLK * DM * DRED * 2;
  bf16* wfc = (bf16*)(ws + off); off += (size_t)KBLK * DM * DM * 2;
  bf16* wcp = (bf16*)(ws + off); off += (size_t)KBLK * DM * DM * 2;
  bf16* wpj = (bf16*)(ws + off); off += (size_t)768 * DM * 2;

  // weight casts (deterministic, every call)
  cast_bf16_kernel<<<4096, 256, 0, stream>>>(ipw, wq, KBLK * 768 * DM);
  cast_bf16_kernel<<<2048, 256, 0, stream>>>(opw, wo, KBLK * DM * DRED);
  cast_bf16_kernel<<<4096, 256, 0, stream>>>(fcw, wfc, KBLK * DM * DM);
  cast_bf16_kernel<<<4096, 256, 0, stream>>>(cpw, wcp, KBLK * DM * DM);
  cast_projT_kernel<<<(768 * DM) / 256, 256, 0, stream>>>(proj, wpj);

  const dim3 g768(MP / 128, 768 / 128);
  const dim3 g1024(MP / 128, DM / 128);

  for (int i = 0; i < KBLK; ++i) {
    const float* hk = hook + (size_t)i * MR * DM;
    if (i == 0)
      ln_kernel<0><<<MR, 256, 0, stream>>>(hk, alpha, i, x, hbuf, l1w + i * DM, l1b + i * DM);
    else
      ln_kernel<1><<<MR, 256, 0, stream>>>(hk, alpha, i, x, hbuf, l1w + i * DM, l1b + i * DM);
    // qkv = LN1(x) @ ipw^T + ipb   (fp32 out)
    gemm_kernel<0><<<g768, 256, 0, stream>>>(hbuf, DM, wq + (size_t)i * 768 * DM, DM,
                                             ipb + i * 768, qkv, 768, DM, MR);
    attn_kernel<<<BA * NHEAD, 256, 0, stream>>>(qkv, obuf);
    // x += attn_out @ opw^T + opb
    gemm_kernel<1><<<g1024, 256, 0, stream>>>(obuf, DRED, wo + (size_t)i * DM * DRED, DRED,
                                              opb + i * DM, x, DM, DRED, MR);
    ln_kernel<2><<<MR, 256, 0, stream>>>(nullptr, nullptr, i, x, hbuf, l2w + i * DM, l2b + i * DM);
    // mbuf = quickgelu(LN2(x) @ fcw^T + fcb)  (bf16)
    gemm_kernel<2><<<g1024, 256, 0, stream>>>(hbuf, DM, wfc + (size_t)i * DM * DM, DM,
                                              fcb + i * DM, mbuf, DM, DM, MR);
    // x += mbuf @ cpw^T + cpb
    gemm_kernel<1><<<g1024, 256, 0, stream>>>(mbuf, DM, wcp + (size_t)i * DM * DM, DM,
                                              cpb + i * DM, x, DM, DM, MR);
  }
  // final: LN_post (transposed to (B,S,D)) then @ proj -> d_out
  ln_kernel<3><<<MR, 256, 0, stream>>>(nullptr, nullptr, 0, x, hbuf, lpw, lpb);
  gemm_kernel<0><<<g768, 256, 0, stream>>>(hbuf, DM, wpj, DM, nullptr,
                                           (float*)d_out, 768, DM, MR);
}

// Round 2
// 2590.222 us; speedup vs baseline: 1.4103x; 1.4103x over previous
//
#include <hip/hip_runtime.h>
#include <hip/hip_bf16.h>
#include <cstdint>
#include <cstddef>

// Problem constants
#define KBLK 6
#define SL 257
#define BA 64
#define DM 1024
#define NHEAD 16
#define DRED 256
#define HDM 16
#define MR (SL * BA)     // 16448 real rows
#define MP 16512         // 129 * 128 padded rows
#define LNEPS 1e-5f

typedef __hip_bfloat16 bf16;
typedef __attribute__((ext_vector_type(8))) short short8;
typedef __attribute__((ext_vector_type(4))) short short4_t;
typedef __attribute__((ext_vector_type(4))) float f32x4;

// ---------------- async global -> LDS (16B per lane) ----------------
__device__ __forceinline__ void gld_lds16(const void* g, void* l) {
  __builtin_amdgcn_global_load_lds(
      (const __attribute__((address_space(1))) unsigned int*)g,
      (__attribute__((address_space(3))) unsigned int*)l, 16, 0, 0);
}

// ---------------- weight casts ----------------
__global__ __launch_bounds__(256) void cast_bf16_kernel(const float* __restrict__ src,
                                                        bf16* __restrict__ dst, int n) {
  int i = blockIdx.x * 256 + threadIdx.x;
  int stride = gridDim.x * 256;
  for (; i < n; i += stride) dst[i] = __float2bfloat16(src[i]);
}

__global__ __launch_bounds__(256) void cast_projT_kernel(const float* __restrict__ proj,
                                                         bf16* __restrict__ dst) {
  // proj: (DM, 768) -> dst: (768, DM)
  int i = blockIdx.x * 256 + threadIdx.x;
  if (i < 768 * DM) {
    int n = i >> 10, k = i & (DM - 1);
    dst[i] = __float2bfloat16(proj[k * 768 + n]);
  }
}

// ---------------- LayerNorm (+gate) ----------------
// MODE 0: x = hook; LN(x) -> hout
// MODE 1: x = wm*hook + (1-wm)*x; LN(x) -> hout
// MODE 2: LN(x) -> hout
// MODE 3: LN(x) -> hout at transposed row (b*SL+s)  [ln_post]
template <int MODE>
__global__ __launch_bounds__(256) void ln_kernel(
    const float* __restrict__ hook, const float* __restrict__ alpha, int kidx,
    float* __restrict__ x, bf16* __restrict__ hout,
    const float* __restrict__ w, const float* __restrict__ bb) {
  const int row = blockIdx.x;
  const int tid = threadIdx.x;
  const size_t base = (size_t)row * DM + tid * 4;
  float4 v;
  if (MODE == 0) {
    v = *(const float4*)(hook + base);
    *(float4*)(x + base) = v;
  } else if (MODE == 1) {
    const float wm = 1.f / (1.f + __expf(-alpha[kidx] * 10.f));
    const float om = 1.f - wm;
    float4 hv = *(const float4*)(hook + base);
    float4 xv = *(const float4*)(x + base);
    v.x = wm * hv.x + om * xv.x;
    v.y = wm * hv.y + om * xv.y;
    v.z = wm * hv.z + om * xv.z;
    v.w = wm * hv.w + om * xv.w;
    *(float4*)(x + base) = v;
  } else {
    v = *(const float4*)(x + base);
  }
  float s1 = v.x + v.y + v.z + v.w;
  float s2 = v.x * v.x + v.y * v.y + v.z * v.z + v.w * v.w;
#pragma unroll
  for (int o = 32; o >= 1; o >>= 1) {
    s1 += __shfl_down(s1, o);
    s2 += __shfl_down(s2, o);
  }
  __shared__ float red[8];
  if ((tid & 63) == 0) {
    red[tid >> 6] = s1;
    red[4 + (tid >> 6)] = s2;
  }
  __syncthreads();
  s1 = red[0] + red[1] + red[2] + red[3];
  s2 = red[4] + red[5] + red[6] + red[7];
  const float mu = s1 * (1.f / DM);
  const float rs = rsqrtf(s2 * (1.f / DM) - mu * mu + LNEPS);
  size_t orow = row;
  if (MODE == 3) {
    int s = row >> 6, b2 = row & 63;
    orow = (size_t)b2 * SL + s;
  }
  const int c = tid * 4;
  float vals[4] = {v.x, v.y, v.z, v.w};
  short4_t pk;
#pragma unroll
  for (int j = 0; j < 4; ++j) {
    float hv = (vals[j] - mu) * rs * w[c + j] + bb[c + j];
    bf16 t = __float2bfloat16(hv);
    pk[j] = *reinterpret_cast<short*>(&t);
  }
  *(short4_t*)((char*)hout + (orow * DM + c) * 2) = pk;
}

// ---------------- MFMA attention ----------------
// Per block: one (b, h). qkv is bf16, rows (s*BA+b)*768, q at +0, k at +256, v at +512.
// Swapped QK^T: S^T[s][q] = mfma(A=K_tile, B=Q_tile). C layout: col=lane&15 (q),
// row=(lane>>4)*4+r (s within 16-tile). Softmax per-lane over 17 tiles * 4 regs,
// cross-lane reduce via shfl_xor(16), shfl_xor(32).
// PV: P back to A-frag layout via tiny per-wave LDS chunk (within-wave, no barrier),
// B-frag = V^T direct from LDS.
__global__ __launch_bounds__(256) void attn_mfma_kernel(const bf16* __restrict__ qkv,
                                                        bf16* __restrict__ obuf) {
  __shared__ __align__(16) short ql[272][24];
  __shared__ __align__(16) short kl[272][24];
  __shared__ __align__(16) short vt[16][296];
  __shared__ __align__(16) short pl[4][16][40];
  const int bh = blockIdx.x;
  const int b = bh >> 4, h = bh & 15;
  const int tid = threadIdx.x;
  const int wave = tid >> 6, lane = tid & 63;
  const int g = lane >> 4, qi = lane & 15;

  const short8 zero8 = {0, 0, 0, 0, 0, 0, 0, 0};
  const f32x4 fzero = {0.f, 0.f, 0.f, 0.f};

  // stage: tasks = 3 arrays * 272 rows * 2 halves = 1632, each task one short8
  for (int task = tid; task < 1632; task += 256) {
    int a, rem;
    if (task < 544) { a = 0; rem = task; }
    else if (task < 1088) { a = 1; rem = task - 544; }
    else { a = 2; rem = task - 1088; }
    int row = rem >> 1, half = rem & 1;
    short8 v = zero8;
    if (row < SL)
      v = *(const short8*)((const short*)qkv + (size_t)(row * BA + b) * 768 + a * 256 + h * 16 + half * 8);
    if (a == 0) *(short8*)&ql[row][half * 8] = v;
    else if (a == 1) *(short8*)&kl[row][half * 8] = v;
    else {
#pragma unroll
      for (int j = 0; j < 8; ++j) vt[half * 8 + j][row] = v[j];
    }
  }
  // zero V^T pad cols [272, 296)
  for (int i = tid; i < 16 * 24; i += 256) vt[i / 24][272 + (i % 24)] = 0;
  __syncthreads();

  for (int t = wave; t < 17; t += 4) {
    // Q B-frag: (k=(lane>>4)*8+j, n=q=lane&15); k>=16 is zero pad
    short8 bq = zero8;
    if (g < 2) bq = *(const short8*)&ql[t * 16 + qi][g * 8];

    f32x4 st[18];
#pragma unroll
    for (int t2 = 0; t2 < 17; ++t2) {
      short8 ak = zero8;
      if (g < 2) ak = *(const short8*)&kl[t2 * 16 + qi][g * 8];
      st[t2] = __builtin_amdgcn_mfma_f32_16x16x32_bf16(ak, bq, fzero, 0, 0, 0);
    }
    // scale + mask + row max (per lane, q = t*16+qi, s = t2*16 + 4g + r)
    float mx = -1e30f;
#pragma unroll
    for (int t2 = 0; t2 < 17; ++t2) {
#pragma unroll
      for (int r = 0; r < 4; ++r) {
        int s = t2 * 16 + g * 4 + r;
        float v = (s <= 256) ? st[t2][r] * 0.25f : -1e30f;
        st[t2][r] = v;
        mx = fmaxf(mx, v);
      }
    }
    mx = fmaxf(mx, __shfl_xor(mx, 16));
    mx = fmaxf(mx, __shfl_xor(mx, 32));
    float ls = 0.f;
#pragma unroll
    for (int t2 = 0; t2 < 17; ++t2) {
#pragma unroll
      for (int r = 0; r < 4; ++r) {
        float p = __expf(st[t2][r] - mx);
        st[t2][r] = p;
        ls += p;
      }
    }
    ls += __shfl_xor(ls, 16);
    ls += __shfl_xor(ls, 32);
    const float inv = 1.f / ls;
#pragma unroll
    for (int t2 = 0; t2 < 17; ++t2)
#pragma unroll
      for (int r = 0; r < 4; ++r) st[t2][r] *= inv;
    st[17] = fzero;

    // PV: per 32-wide s chunk: write P chunk to per-wave LDS, read back in A-frag layout
    f32x4 acc = fzero;
#pragma unroll
    for (int tt = 0; tt < 9; ++tt) {
#pragma unroll
      for (int hh = 0; hh < 2; ++hh) {
        int t2 = tt * 2 + hh;
        short4_t pk;
#pragma unroll
        for (int r = 0; r < 4; ++r) {
          bf16 tb = __float2bfloat16(st[t2][r]);
          pk[r] = *reinterpret_cast<short*>(&tb);
        }
        *(short4_t*)&pl[wave][qi][hh * 16 + g * 4] = pk;
      }
      short8 pa = *(const short8*)&pl[wave][qi][g * 8];
      short8 bv = *(const short8*)&vt[qi][tt * 32 + g * 8];
      acc = __builtin_amdgcn_mfma_f32_16x16x32_bf16(pa, bv, acc, 0, 0, 0);
    }
    // store: O[q = t*16 + 4g + r][d = qi]
#pragma unroll
    for (int r = 0; r < 4; ++r) {
      int qr = t * 16 + g * 4 + r;
      if (qr < SL)
        obuf[(size_t)(qr * BA + b) * DRED + h * 16 + qi] = __float2bfloat16(acc[r]);
    }
  }
}

// ---------------- GEMM: C(M,N) = A(M,K) * Bw(N,K)^T + bias ----------------
// EPI 0: write fp32 C (+bias)
// EPI 1: C(fp32) += acc + bias   (residual accumulate)
// EPI 2: write bf16 quickgelu(acc+bias)
// EPI 3: write bf16 (acc+bias)
template <int EPI>
__global__ __launch_bounds__(256) void gemm_kernel(
    const bf16* __restrict__ A, int lda,
    const bf16* __restrict__ Bw, int ldb,
    const float* __restrict__ bias,
    void* __restrict__ C, int ldc,
    int Kdim, int Mreal) {
  __shared__ char lds[2 * 32768];  // [buf][A 16KB | B 16KB], BK=64
  const int tid = threadIdx.x;
  const int wave = tid >> 6, lane = tid & 63;
  const int lrow = lane & 15, lk = lane >> 4;
  const int wr = wave >> 1, wc = wave & 1;
  const int m0 = blockIdx.x * 128;
  const int n0 = blockIdx.y * 128;

  f32x4 acc[4][4];
  const f32x4 zero = {0.f, 0.f, 0.f, 0.f};
#pragma unroll
  for (int i = 0; i < 4; ++i)
#pragma unroll
    for (int j = 0; j < 4; ++j) acc[i][j] = zero;

  const int nk = Kdim >> 6;

  auto stage = [&](int buf, int kt) {
    const int k0 = kt << 6;
#pragma unroll
    for (int j = 0; j < 4; ++j) {
      int c = wave * 256 + j * 64 + lane;
      int row = c >> 3, segp = c & 7;
      int seg = segp ^ (row & 7);
      const bf16* ga = A + (size_t)(m0 + row) * lda + k0 + seg * 8;
      gld_lds16(ga, &lds[buf * 32768 + (wave * 256 + j * 64) * 16]);
      const bf16* gb = Bw + (size_t)(n0 + row) * ldb + k0 + seg * 8;
      gld_lds16(gb, &lds[buf * 32768 + 16384 + (wave * 256 + j * 64) * 16]);
    }
  };

  stage(0, 0);
  __syncthreads();
  int cur = 0;
  for (int kt = 0; kt < nk; ++kt) {
    if (kt + 1 < nk) stage(cur ^ 1, kt + 1);
    const char* aL = &lds[cur * 32768];
    const char* bL = aL + 16384;
#pragma unroll
    for (int kh = 0; kh < 2; ++kh) {
      short8 af[4], bfr[4];
#pragma unroll
      for (int i = 0; i < 4; ++i) {
        int r = wr * 64 + i * 16 + lrow;
        int seg = kh * 4 + lk;
        af[i] = *(const short8*)(aL + r * 128 + ((seg ^ (r & 7)) << 4));
      }
#pragma unroll
      for (int j = 0; j < 4; ++j) {
        int r = wc * 64 + j * 16 + lrow;
        int seg = kh * 4 + lk;
        bfr[j] = *(const short8*)(bL + r * 128 + ((seg ^ (r & 7)) << 4));
      }
#pragma unroll
      for (int i = 0; i < 4; ++i)
#pragma unroll
        for (int j = 0; j < 4; ++j)
          acc[i][j] = __builtin_amdgcn_mfma_f32_16x16x32_bf16(af[i], bfr[j], acc[i][j], 0, 0, 0);
    }
    __syncthreads();
    cur ^= 1;
  }

#pragma unroll
  for (int i = 0; i < 4; ++i) {
#pragma unroll
    for (int j = 0; j < 4; ++j) {
      int col = n0 + wc * 64 + j * 16 + lrow;
      float bv = bias ? bias[col] : 0.f;
#pragma unroll
      for (int r = 0; r < 4; ++r) {
        int row = m0 + wr * 64 + i * 16 + lk * 4 + r;
        if (row < Mreal) {
          float v = acc[i][j][r] + bv;
          size_t off = (size_t)row * ldc + col;
          if (EPI == 0) {
            ((float*)C)[off] = v;
          } else if (EPI == 1) {
            float* p = (float*)C + off;
            *p += v;
          } else if (EPI == 2) {
            float g2 = v / (1.f + __expf(-1.702f * v));
            ((bf16*)C)[off] = __float2bfloat16(g2);
          } else {
            ((bf16*)C)[off] = __float2bfloat16(v);
          }
        }
      }
    }
  }
}

// ---------------- driver ----------------
extern "C" void kernel_launch(void* const* d_in, const int* in_sizes, int n_in,
                              void* d_out, int out_size, void* d_ws, size_t ws_size,
                              hipStream_t stream) {
  const float* hook = (const float*)d_in[0];
  const float* alpha = (const float*)d_in[1];
  const float* ipw = (const float*)d_in[2];
  const float* ipb = (const float*)d_in[3];
  const float* opw = (const float*)d_in[4];
  const float* opb = (const float*)d_in[5];
  const float* l1w = (const float*)d_in[6];
  const float* l1b = (const float*)d_in[7];
  const float* l2w = (const float*)d_in[8];
  const float* l2b = (const float*)d_in[9];
  const float* fcw = (const float*)d_in[10];
  const float* fcb = (const float*)d_in[11];
  const float* cpw = (const float*)d_in[12];
  const float* cpb = (const float*)d_in[13];
  const float* lpw = (const float*)d_in[14];
  const float* lpb = (const float*)d_in[15];
  const float* proj = (const float*)d_in[16];

  char* ws = (char*)d_ws;
  size_t off = 0;
  float* x = (float*)(ws + off); off += (size_t)MP * DM * 4;
  bf16* hbuf = (bf16*)(ws + off); off += (size_t)MP * DM * 2;
  bf16* qkv = (bf16*)(ws + off);
  bf16* mbuf = (bf16*)qkv;  // reuse qkv region for MLP intermediate (bf16)
  off += (size_t)MP * 768 * 4;
  bf16* obuf = (bf16*)(ws + off); off += (size_t)MP * DRED * 2;
  bf16* wq = (bf16*)(ws + off); off += (size_t)KBLK * 768 * DM * 2;
  bf16* wo = (bf16*)(ws + off); off += (size_t)KBLK * DM * DRED * 2;
  bf16* wfc = (bf16*)(ws + off); off += (size_t)KBLK * DM * DM * 2;
  bf16* wcp = (bf16*)(ws + off); off += (size_t)KBLK * DM * DM * 2;
  bf16* wpj = (bf16*)(ws + off); off += (size_t)768 * DM * 2;

  // weight casts (deterministic, every call)
  cast_bf16_kernel<<<4096, 256, 0, stream>>>(ipw, wq, KBLK * 768 * DM);
  cast_bf16_kernel<<<2048, 256, 0, stream>>>(opw, wo, KBLK * DM * DRED);
  cast_bf16_kernel<<<4096, 256, 0, stream>>>(fcw, wfc, KBLK * DM * DM);
  cast_bf16_kernel<<<4096, 256, 0, stream>>>(cpw, wcp, KBLK * DM * DM);
  cast_projT_kernel<<<(768 * DM) / 256, 256, 0, stream>>>(proj, wpj);

  const dim3 g768(MP / 128, 768 / 128);
  const dim3 g1024(MP / 128, DM / 128);

  for (int i = 0; i < KBLK; ++i) {
    const float* hk = hook + (size_t)i * MR * DM;
    if (i == 0)
      ln_kernel<0><<<MR, 256, 0, stream>>>(hk, alpha, i, x, hbuf, l1w + i * DM, l1b + i * DM);
    else
      ln_kernel<1><<<MR, 256, 0, stream>>>(hk, alpha, i, x, hbuf, l1w + i * DM, l1b + i * DM);
    // qkv = LN1(x) @ ipw^T + ipb   (bf16 out)
    gemm_kernel<3><<<g768, 256, 0, stream>>>(hbuf, DM, wq + (size_t)i * 768 * DM, DM,
                                             ipb + i * 768, qkv, 768, DM, MR);
    attn_mfma_kernel<<<BA * NHEAD, 256, 0, stream>>>(qkv, obuf);
    // x += attn_out @ opw^T + opb
    gemm_kernel<1><<<g1024, 256, 0, stream>>>(obuf, DRED, wo + (size_t)i * DM * DRED, DRED,
                                              opb + i * DM, x, DM, DRED, MR);
    ln_kernel<2><<<MR, 256, 0, stream>>>(nullptr, nullptr, i, x, hbuf, l2w + i * DM, l2b + i * DM);
    // mbuf = quickgelu(LN2(x) @ fcw^T + fcb)  (bf16)
    gemm_kernel<2><<<g1024, 256, 0, stream>>>(hbuf, DM, wfc + (size_t)i * DM * DM, DM,
                                              fcb + i * DM, mbuf, DM, DM, MR);
    // x += mbuf @ cpw^T + cpb
    gemm_kernel<1><<<g1024, 256, 0, stream>>>(mbuf, DM, wcp + (size_t)i * DM * DM, DM,
                                              cpb + i * DM, x, DM, DM, MR);
  }
  // final: LN_post (transposed to (B,S,D)) then @ proj -> d_out
  ln_kernel<3><<<MR, 256, 0, stream>>>(nullptr, nullptr, 0, x, hbuf, lpw, lpb);
  gemm_kernel<0><<<g768, 256, 0, stream>>>(hbuf, DM, wpj, DM, nullptr,
                                           (float*)d_out, 768, DM, MR);
}

// Round 3
// 2117.980 us; speedup vs baseline: 1.7248x; 1.2230x over previous
//
#include <hip/hip_runtime.h>
#include <hip/hip_bf16.h>
#include <cstdint>
#include <cstddef>

// Problem constants
#define KBLK 6
#define SL 257
#define BA 64
#define DM 1024
#define NHEAD 16
#define DRED 256
#define HDM 16
#define MR (SL * BA)     // 16448 real rows
#define MP 16512         // 129 * 128 padded rows
#define LNEPS 1e-5f

typedef __hip_bfloat16 bf16;
typedef __attribute__((ext_vector_type(8))) short short8;
typedef __attribute__((ext_vector_type(4))) short short4_t;
typedef __attribute__((ext_vector_type(4))) float f32x4;

// ---------------- async global -> LDS (16B per lane) ----------------
__device__ __forceinline__ void gld_lds16(const void* g, void* l) {
  __builtin_amdgcn_global_load_lds(
      (const __attribute__((address_space(1))) unsigned int*)g,
      (__attribute__((address_space(3))) unsigned int*)l, 16, 0, 0);
}

__device__ __forceinline__ float bf2f(short s) {
  bf16 t = *reinterpret_cast<bf16*>(&s);
  return __bfloat162float(t);
}
__device__ __forceinline__ short f2bf(float f) {
  bf16 t = __float2bfloat16(f);
  return *reinterpret_cast<short*>(&t);
}

// ---------------- weight casts ----------------
__global__ __launch_bounds__(256) void cast_bf16_kernel(const float* __restrict__ src,
                                                        bf16* __restrict__ dst, int n) {
  int i = blockIdx.x * 256 + threadIdx.x;
  int stride = gridDim.x * 256;
  for (; i < n; i += stride) dst[i] = __float2bfloat16(src[i]);
}

__global__ __launch_bounds__(256) void cast_projT_kernel(const float* __restrict__ proj,
                                                         bf16* __restrict__ dst) {
  // proj: (DM, 768) -> dst: (768, DM)
  int i = blockIdx.x * 256 + threadIdx.x;
  if (i < 768 * DM) {
    int n = i >> 10, k = i & (DM - 1);
    dst[i] = __float2bfloat16(proj[k * 768 + n]);
  }
}

// ---------------- LayerNorm ----------------
// x is bf16 residual stream.
// MODE 0: x = hook (bf16); LN(hook fp32) -> hout
// MODE 2: LN(x) -> hout
// MODE 3: LN(x) -> hout at transposed row (b*SL+s)  [ln_post]
template <int MODE>
__global__ __launch_bounds__(256) void ln_kernel(
    const float* __restrict__ hook,
    bf16* __restrict__ x, bf16* __restrict__ hout,
    const float* __restrict__ w, const float* __restrict__ bb) {
  const int row = blockIdx.x;
  const int tid = threadIdx.x;
  const size_t base = (size_t)row * DM + tid * 4;
  float vals[4];
  if (MODE == 0) {
    float4 v = *(const float4*)(hook + base);
    vals[0] = v.x; vals[1] = v.y; vals[2] = v.z; vals[3] = v.w;
    short4_t pk;
#pragma unroll
    for (int j = 0; j < 4; ++j) pk[j] = f2bf(vals[j]);
    *(short4_t*)&x[base] = pk;
  } else {
    short4_t xv = *(const short4_t*)&x[base];
#pragma unroll
    for (int j = 0; j < 4; ++j) vals[j] = bf2f(xv[j]);
  }
  float s1 = vals[0] + vals[1] + vals[2] + vals[3];
  float s2 = vals[0] * vals[0] + vals[1] * vals[1] + vals[2] * vals[2] + vals[3] * vals[3];
#pragma unroll
  for (int o = 32; o >= 1; o >>= 1) {
    s1 += __shfl_down(s1, o);
    s2 += __shfl_down(s2, o);
  }
  __shared__ float red[8];
  if ((tid & 63) == 0) {
    red[tid >> 6] = s1;
    red[4 + (tid >> 6)] = s2;
  }
  __syncthreads();
  s1 = red[0] + red[1] + red[2] + red[3];
  s2 = red[4] + red[5] + red[6] + red[7];
  const float mu = s1 * (1.f / DM);
  const float rs = rsqrtf(s2 * (1.f / DM) - mu * mu + LNEPS);
  size_t orow = row;
  if (MODE == 3) {
    int s = row >> 6, b2 = row & 63;
    orow = (size_t)b2 * SL + s;
  }
  const int c = tid * 4;
  short4_t pk;
#pragma unroll
  for (int j = 0; j < 4; ++j)
    pk[j] = f2bf((vals[j] - mu) * rs * w[c + j] + bb[c + j]);
  *(short4_t*)((char*)hout + (orow * DM + c) * 2) = pk;
}

// ---------------- MFMA attention ----------------
// Per block: one (b, h). qkv is bf16, rows (s*BA+b)*768, q at +0, k at +256, v at +512.
// Swapped QK^T: S^T = mfma(A=K_tile, B=Q_tile); softmax per-lane + shfl_xor(16/32).
// PV: P to A-frag layout via per-wave LDS chunk (within-wave), B-frag = V^T from LDS.
__global__ __launch_bounds__(256) void attn_mfma_kernel(const bf16* __restrict__ qkv,
                                                        bf16* __restrict__ obuf) {
  __shared__ __align__(16) short ql[272][24];
  __shared__ __align__(16) short kl[272][24];
  __shared__ __align__(16) short vt[16][296];
  __shared__ __align__(16) short pl[4][16][40];
  const int bh = blockIdx.x;
  const int b = bh >> 4, h = bh & 15;
  const int tid = threadIdx.x;
  const int wave = tid >> 6, lane = tid & 63;
  const int g = lane >> 4, qi = lane & 15;

  const short8 zero8 = {0, 0, 0, 0, 0, 0, 0, 0};
  const f32x4 fzero = {0.f, 0.f, 0.f, 0.f};

  for (int task = tid; task < 1632; task += 256) {
    int a, rem;
    if (task < 544) { a = 0; rem = task; }
    else if (task < 1088) { a = 1; rem = task - 544; }
    else { a = 2; rem = task - 1088; }
    int row = rem >> 1, half = rem & 1;
    short8 v = zero8;
    if (row < SL)
      v = *(const short8*)((const short*)qkv + (size_t)(row * BA + b) * 768 + a * 256 + h * 16 + half * 8);
    if (a == 0) *(short8*)&ql[row][half * 8] = v;
    else if (a == 1) *(short8*)&kl[row][half * 8] = v;
    else {
#pragma unroll
      for (int j = 0; j < 8; ++j) vt[half * 8 + j][row] = v[j];
    }
  }
  for (int i = tid; i < 16 * 24; i += 256) vt[i / 24][272 + (i % 24)] = 0;
  __syncthreads();

  for (int t = wave; t < 17; t += 4) {
    short8 bq = zero8;
    if (g < 2) bq = *(const short8*)&ql[t * 16 + qi][g * 8];

    f32x4 st[18];
#pragma unroll
    for (int t2 = 0; t2 < 17; ++t2) {
      short8 ak = zero8;
      if (g < 2) ak = *(const short8*)&kl[t2 * 16 + qi][g * 8];
      st[t2] = __builtin_amdgcn_mfma_f32_16x16x32_bf16(ak, bq, fzero, 0, 0, 0);
    }
    float mx = -1e30f;
#pragma unroll
    for (int t2 = 0; t2 < 17; ++t2) {
#pragma unroll
      for (int r = 0; r < 4; ++r) {
        int s = t2 * 16 + g * 4 + r;
        float v = (s <= 256) ? st[t2][r] * 0.25f : -1e30f;
        st[t2][r] = v;
        mx = fmaxf(mx, v);
      }
    }
    mx = fmaxf(mx, __shfl_xor(mx, 16));
    mx = fmaxf(mx, __shfl_xor(mx, 32));
    float ls = 0.f;
#pragma unroll
    for (int t2 = 0; t2 < 17; ++t2) {
#pragma unroll
      for (int r = 0; r < 4; ++r) {
        float p = __expf(st[t2][r] - mx);
        st[t2][r] = p;
        ls += p;
      }
    }
    ls += __shfl_xor(ls, 16);
    ls += __shfl_xor(ls, 32);
    const float inv = 1.f / ls;
#pragma unroll
    for (int t2 = 0; t2 < 17; ++t2)
#pragma unroll
      for (int r = 0; r < 4; ++r) st[t2][r] *= inv;
    st[17] = fzero;

    f32x4 acc = fzero;
#pragma unroll
    for (int tt = 0; tt < 9; ++tt) {
#pragma unroll
      for (int hh = 0; hh < 2; ++hh) {
        int t2 = tt * 2 + hh;
        short4_t pk;
#pragma unroll
        for (int r = 0; r < 4; ++r) pk[r] = f2bf(st[t2][r]);
        *(short4_t*)&pl[wave][qi][hh * 16 + g * 4] = pk;
      }
      short8 pa = *(const short8*)&pl[wave][qi][g * 8];
      short8 bv = *(const short8*)&vt[qi][tt * 32 + g * 8];
      acc = __builtin_amdgcn_mfma_f32_16x16x32_bf16(pa, bv, acc, 0, 0, 0);
    }
#pragma unroll
    for (int r = 0; r < 4; ++r) {
      int qr = t * 16 + g * 4 + r;
      if (qr < SL)
        obuf[(size_t)(qr * BA + b) * DRED + h * 16 + qi] = __float2bfloat16(acc[r]);
    }
  }
}

// ---------------- GEMM: C(M,N) = A(M,K) * Bw(N,K)^T + bias ----------------
// m97 structure: single 32KB LDS buffer, stage -> barrier -> compute -> barrier,
// 3 wg/CU. XCD-bijective swizzle with n-fastest decomposition (B stays L2-resident,
// each XCD streams a contiguous A-stripe).
// EPI 0: write fp32 C (+bias)
// EPI 1: C(bf16) += acc + bias        (residual accumulate, bf16 x)
// EPI 2: write bf16 quickgelu(acc+bias)
// EPI 3: write bf16 (acc+bias)
// EPI 4: x = wm*hook + (1-wm)*(x + acc + bias)   (gated residual, bf16 x)
template <int EPI>
__global__ __launch_bounds__(256, 3) void gemm_kernel(
    const bf16* __restrict__ A, int lda,
    const bf16* __restrict__ Bw, int ldb,
    const float* __restrict__ bias,
    void* __restrict__ C, int ldc,
    int Kdim, int Mreal,
    const float* __restrict__ hook, const float* __restrict__ alpha, int kidx) {
  __shared__ char lds[32768];  // A 16KB | B 16KB, BK=64
  const int tid = threadIdx.x;
  const int wave = tid >> 6, lane = tid & 63;
  const int lrow = lane & 15, lk = lane >> 4;
  const int wr = wave >> 1, wc = wave & 1;

  // XCD-aware bijective swizzle (m204), n-fastest decomposition
  const int gx = gridDim.x, gy = gridDim.y;
  const int nwg = gx * gy;
  const int orig = blockIdx.y * gx + blockIdx.x;
  const int q = nwg >> 3, r = nwg & 7;
  const int xcd = orig & 7, idx = orig >> 3;
  const int wgid = (xcd < r ? xcd * (q + 1) : r * (q + 1) + (xcd - r) * q) + idx;
  const int m0 = (wgid / gy) * 128;
  const int n0 = (wgid % gy) * 128;

  f32x4 acc[4][4];
  const f32x4 zero = {0.f, 0.f, 0.f, 0.f};
#pragma unroll
  for (int i = 0; i < 4; ++i)
#pragma unroll
    for (int j = 0; j < 4; ++j) acc[i][j] = zero;

  const int nk = Kdim >> 6;

  for (int kt = 0; kt < nk; ++kt) {
    const int k0 = kt << 6;
#pragma unroll
    for (int j = 0; j < 4; ++j) {
      int c = wave * 256 + j * 64 + lane;
      int row = c >> 3, segp = c & 7;
      int seg = segp ^ (row & 7);
      const bf16* ga = A + (size_t)(m0 + row) * lda + k0 + seg * 8;
      gld_lds16(ga, &lds[(wave * 256 + j * 64) * 16]);
      const bf16* gb = Bw + (size_t)(n0 + row) * ldb + k0 + seg * 8;
      gld_lds16(gb, &lds[16384 + (wave * 256 + j * 64) * 16]);
    }
    __syncthreads();
    const char* aL = &lds[0];
    const char* bL = aL + 16384;
#pragma unroll
    for (int kh = 0; kh < 2; ++kh) {
      short8 af[4], bfr[4];
#pragma unroll
      for (int i = 0; i < 4; ++i) {
        int rr = wr * 64 + i * 16 + lrow;
        int seg = kh * 4 + lk;
        af[i] = *(const short8*)(aL + rr * 128 + ((seg ^ (rr & 7)) << 4));
      }
#pragma unroll
      for (int j = 0; j < 4; ++j) {
        int rr = wc * 64 + j * 16 + lrow;
        int seg = kh * 4 + lk;
        bfr[j] = *(const short8*)(bL + rr * 128 + ((seg ^ (rr & 7)) << 4));
      }
#pragma unroll
      for (int i = 0; i < 4; ++i)
#pragma unroll
        for (int j = 0; j < 4; ++j)
          acc[i][j] = __builtin_amdgcn_mfma_f32_16x16x32_bf16(af[i], bfr[j], acc[i][j], 0, 0, 0);
    }
    __syncthreads();
  }

  float wm = 0.f, om = 0.f;
  if (EPI == 4) {
    wm = 1.f / (1.f + __expf(-alpha[kidx] * 10.f));
    om = 1.f - wm;
  }
#pragma unroll
  for (int i = 0; i < 4; ++i) {
#pragma unroll
    for (int j = 0; j < 4; ++j) {
      int col = n0 + wc * 64 + j * 16 + lrow;
      float bv = bias ? bias[col] : 0.f;
#pragma unroll
      for (int rr = 0; rr < 4; ++rr) {
        int row = m0 + wr * 64 + i * 16 + lk * 4 + rr;
        if (row < Mreal) {
          float v = acc[i][j][rr] + bv;
          size_t off = (size_t)row * ldc + col;
          if (EPI == 0) {
            ((float*)C)[off] = v;
          } else if (EPI == 1) {
            bf16* p = (bf16*)C + off;
            *p = __float2bfloat16(__bfloat162float(*p) + v);
          } else if (EPI == 2) {
            float g2 = v / (1.f + __expf(-1.702f * v));
            ((bf16*)C)[off] = __float2bfloat16(g2);
          } else if (EPI == 3) {
            ((bf16*)C)[off] = __float2bfloat16(v);
          } else {  // EPI 4: gated residual
            bf16* p = (bf16*)C + off;
            float t = __bfloat162float(*p) + v;
            *p = __float2bfloat16(wm * hook[off] + om * t);
          }
        }
      }
    }
  }
}

// ---------------- driver ----------------
extern "C" void kernel_launch(void* const* d_in, const int* in_sizes, int n_in,
                              void* d_out, int out_size, void* d_ws, size_t ws_size,
                              hipStream_t stream) {
  const float* hook = (const float*)d_in[0];
  const float* alpha = (const float*)d_in[1];
  const float* ipw = (const float*)d_in[2];
  const float* ipb = (const float*)d_in[3];
  const float* opw = (const float*)d_in[4];
  const float* opb = (const float*)d_in[5];
  const float* l1w = (const float*)d_in[6];
  const float* l1b = (const float*)d_in[7];
  const float* l2w = (const float*)d_in[8];
  const float* l2b = (const float*)d_in[9];
  const float* fcw = (const float*)d_in[10];
  const float* fcb = (const float*)d_in[11];
  const float* cpw = (const float*)d_in[12];
  const float* cpb = (const float*)d_in[13];
  const float* lpw = (const float*)d_in[14];
  const float* lpb = (const float*)d_in[15];
  const float* proj = (const float*)d_in[16];

  char* ws = (char*)d_ws;
  size_t off = 0;
  bf16* x = (bf16*)(ws + off); off += (size_t)MP * DM * 2;
  bf16* hbuf = (bf16*)(ws + off); off += (size_t)MP * DM * 2;
  bf16* qkv = (bf16*)(ws + off);
  bf16* mbuf = (bf16*)qkv;  // reuse qkv region for MLP intermediate (bf16)
  off += (size_t)MP * 1024 * 2;
  bf16* obuf = (bf16*)(ws + off); off += (size_t)MP * DRED * 2;
  bf16* wq = (bf16*)(ws + off); off += (size_t)KBLK * 768 * DM * 2;
  bf16* wo = (bf16*)(ws + off); off += (size_t)KBLK * DM * DRED * 2;
  bf16* wfc = (bf16*)(ws + off); off += (size_t)KBLK * DM * DM * 2;
  bf16* wcp = (bf16*)(ws + off); off += (size_t)KBLK * DM * DM * 2;
  bf16* wpj = (bf16*)(ws + off); off += (size_t)768 * DM * 2;

  // weight casts (deterministic, every call)
  cast_bf16_kernel<<<4096, 256, 0, stream>>>(ipw, wq, KBLK * 768 * DM);
  cast_bf16_kernel<<<2048, 256, 0, stream>>>(opw, wo, KBLK * DM * DRED);
  cast_bf16_kernel<<<4096, 256, 0, stream>>>(fcw, wfc, KBLK * DM * DM);
  cast_bf16_kernel<<<4096, 256, 0, stream>>>(cpw, wcp, KBLK * DM * DM);
  cast_projT_kernel<<<(768 * DM) / 256, 256, 0, stream>>>(proj, wpj);

  const dim3 g768(MP / 128, 768 / 128);
  const dim3 g1024(MP / 128, DM / 128);

  for (int i = 0; i < KBLK; ++i) {
    // LN1: block 0 copies hook into x; blocks >0 read gated x (gate fused in prev cproj)
    if (i == 0)
      ln_kernel<0><<<MR, 256, 0, stream>>>(hook, x, hbuf, l1w, l1b);
    else
      ln_kernel<2><<<MR, 256, 0, stream>>>(nullptr, x, hbuf, l1w + i * DM, l1b + i * DM);
    // qkv = LN1(x) @ ipw^T + ipb   (bf16 out)
    gemm_kernel<3><<<g768, 256, 0, stream>>>(hbuf, DM, wq + (size_t)i * 768 * DM, DM,
                                             ipb + i * 768, qkv, 768, DM, MR,
                                             nullptr, nullptr, 0);
    attn_mfma_kernel<<<BA * NHEAD, 256, 0, stream>>>(qkv, obuf);
    // x += attn_out @ opw^T + opb
    gemm_kernel<1><<<g1024, 256, 0, stream>>>(obuf, DRED, wo + (size_t)i * DM * DRED, DRED,
                                              opb + i * DM, x, DM, DRED, MR,
                                              nullptr, nullptr, 0);
    ln_kernel<2><<<MR, 256, 0, stream>>>(nullptr, x, hbuf, l2w + i * DM, l2b + i * DM);
    // mbuf = quickgelu(LN2(x) @ fcw^T + fcb)  (bf16)
    gemm_kernel<2><<<g1024, 256, 0, stream>>>(hbuf, DM, wfc + (size_t)i * DM * DM, DM,
                                              fcb + i * DM, mbuf, DM, DM, MR,
                                              nullptr, nullptr, 0);
    // x += mbuf @ cpw^T + cpb ; for i<5 also apply next block's ladder gate
    if (i + 1 < KBLK)
      gemm_kernel<4><<<g1024, 256, 0, stream>>>(mbuf, DM, wcp + (size_t)i * DM * DM, DM,
                                                cpb + i * DM, x, DM, DM, MR,
                                                hook + (size_t)(i + 1) * MR * DM, alpha, i + 1);
    else
      gemm_kernel<1><<<g1024, 256, 0, stream>>>(mbuf, DM, wcp + (size_t)i * DM * DM, DM,
                                                cpb + i * DM, x, DM, DM, MR,
                                                nullptr, nullptr, 0);
  }
  // final: LN_post (transposed to (B,S,D)) then @ proj -> d_out
  ln_kernel<3><<<MR, 256, 0, stream>>>(nullptr, x, hbuf, lpw, lpb);
  gemm_kernel<0><<<g768, 256, 0, stream>>>(hbuf, DM, wpj, DM, nullptr,
                                           (float*)d_out, 768, DM, MR,
                                           nullptr, nullptr, 0);
}